// Round 11
// baseline (982.538 us; speedup 1.0000x reference)
//
#include <hip/hip_runtime.h>
#include <hip/hip_bf16.h>
#include <hip/hip_fp16.h>

#define TT 512
#define DD 256
#define NH 4
#define NN 4096
#define VV 256
#define NLAYER 6
#define BB 2
#define BH (BB * NH)
#define NPAIR 2048

typedef __attribute__((ext_vector_type(8))) short bf16x8;
typedef __attribute__((ext_vector_type(4))) float f32x4;
typedef __attribute__((ext_vector_type(8))) unsigned short us8;
typedef __attribute__((ext_vector_type(4))) unsigned short us4;

#define AS1 __attribute__((address_space(1)))
#define AS3 __attribute__((address_space(3)))

__device__ __forceinline__ void glds16(const unsigned short* g, unsigned short* l) {
  __builtin_amdgcn_global_load_lds((const AS1 void*)g, (AS3 void*)l, 16, 0, 0);
}

__device__ __forceinline__ unsigned short f2bf(float f) {
  unsigned int u = __float_as_uint(f);
  return (unsigned short)((u + 0x7FFFu + ((u >> 16) & 1u)) >> 16);
}
__device__ __forceinline__ float bf2f(unsigned short h) {
  return __uint_as_float((unsigned int)h << 16);
}
__device__ __forceinline__ float h2f(unsigned short h) {
  __half x = *reinterpret_cast<__half*>(&h);
  return __half2float(x);
}

// ---------------- block-wide sum over 256 threads ----------------
__device__ __forceinline__ float block_sum_256(float v) {
  __shared__ float s[4];
  #pragma unroll
  for (int o = 32; o > 0; o >>= 1) v += __shfl_down(v, o);
  int lane = threadIdx.x & 63, wid = threadIdx.x >> 6;
  if (lane == 0) s[wid] = v;
  __syncthreads();
  float r = s[0] + s[1] + s[2] + s[3];
  __syncthreads();
  return r;
}

// ---------------- wave-local sum over 64 lanes (no barriers) -------------
__device__ __forceinline__ float wave_sum64(float v) {
  #pragma unroll
  for (int o = 32; o > 0; o >>= 1) v += __shfl_xor(v, o);
  return v;
}

// ---- 128x128 MFMA tile, BK=64 DOUBLE-BUFFERED, WAVE-ROW mapping (R6-proven):
//      wave w owns output rows [w*32,w*32+32), all 128 cols -> acc[2][8].
//      One __syncthreads per k-step; next tile's glds issued before compute.
//      K order ascending 32-slices -> bit-identical accumulation.
__device__ __forceinline__ void mfma_tile128_w32_dbuf(const unsigned short* __restrict__ A, int lda,
                                                      const unsigned short* __restrict__ B, int ldb,
                                                      int K, f32x4 acc[2][8],
                                                      unsigned short* As, unsigned short* Bs) {
  const int tid = threadIdx.x;
  const int lane = tid & 63, wave = tid >> 6;
  const int fm = lane & 15, fq = lane >> 4;
  const int wrow = wave << 5;
  const int lrow = lane >> 3;                        // row within 8-row group
  const int scol = (((lane & 7) ^ lrow) << 3);       // pre-swizzled source col (elems)
  const unsigned short* gA = A + (size_t)(wave * 8 + lrow) * lda + scol;
  const unsigned short* gB = B + (size_t)(wave * 8 + lrow) * ldb + scol;
  const int lbase = wave * 512;
  const int swz = (fm & 7) << 4;                     // read-side XOR (bits 4..6)
  #pragma unroll
  for (int i = 0; i < 4; ++i) {
    glds16(gA + (size_t)(i * 32) * lda, As + lbase + i * 2048);
    glds16(gB + (size_t)(i * 32) * ldb, Bs + lbase + i * 2048);
  }
  __syncthreads();
  int cur = 0;
  for (int k0 = 0; k0 < K; k0 += 64) {
    if (k0 + 64 < K) {
      unsigned short* nA = As + (cur ^ 1) * 8192 + lbase;
      unsigned short* nB = Bs + (cur ^ 1) * 8192 + lbase;
      #pragma unroll
      for (int i = 0; i < 4; ++i) {
        glds16(gA + (k0 + 64) + (size_t)(i * 32) * lda, nA + i * 2048);
        glds16(gB + (k0 + 64) + (size_t)(i * 32) * ldb, nB + i * 2048);
      }
    }
    const char* cA = (const char*)(As + cur * 8192);
    const char* cB = (const char*)(Bs + cur * 8192);
    #pragma unroll
    for (int kk = 0; kk < 2; ++kk) {
      bf16x8 af[2], bfv[8];
      #pragma unroll
      for (int i = 0; i < 2; ++i) {
        const int ra = wrow + i * 16 + fm;
        af[i] = *(const bf16x8*)(cA + ((((ra << 7) + (kk << 6) + (fq << 4))) ^ swz));
      }
      #pragma unroll
      for (int i = 0; i < 8; ++i) {
        const int rb = i * 16 + fm;
        bfv[i] = *(const bf16x8*)(cB + ((((rb << 7) + (kk << 6) + (fq << 4))) ^ swz));
      }
      #pragma unroll
      for (int mi = 0; mi < 2; ++mi)
        #pragma unroll
        for (int ni = 0; ni < 8; ++ni)
          acc[mi][ni] = __builtin_amdgcn_mfma_f32_16x16x32_bf16(af[mi], bfv[ni], acc[mi][ni], 0, 0, 0);
    }
    __syncthreads();   // drains next-stage glds; protects buffer reuse
    cur ^= 1;
  }
}
// C/D: row = m0 + wave*32 + mi*16 + fq*4 + r ; col = n0 + ni*16 + fm

// ---- 128x128 MFMA tile, BK=64 DOUBLE-BUFFERED, 4x4 wave-quadrant mapping.
__device__ __forceinline__ void mfma_tile128_dbuf(const unsigned short* __restrict__ A, int lda,
                                                  const unsigned short* __restrict__ B, int ldb,
                                                  int K, f32x4 acc[4][4],
                                                  unsigned short* As, unsigned short* Bs) {
  const int tid = threadIdx.x;
  const int lane = tid & 63, wave = tid >> 6;
  const int fm = lane & 15, fq = lane >> 4;
  const int rw = (wave >> 1) << 6, cw = (wave & 1) << 6;
  const int lrow = lane >> 3;
  const int scol = (((lane & 7) ^ lrow) << 3);
  const unsigned short* gA = A + (size_t)(wave * 8 + lrow) * lda + scol;
  const unsigned short* gB = B + (size_t)(wave * 8 + lrow) * ldb + scol;
  const int lbase = wave * 512;
  const int swz = (fm & 7) << 4;
  #pragma unroll
  for (int i = 0; i < 4; ++i) {
    glds16(gA + (size_t)(i * 32) * lda, As + lbase + i * 2048);
    glds16(gB + (size_t)(i * 32) * ldb, Bs + lbase + i * 2048);
  }
  __syncthreads();
  int cur = 0;
  for (int k0 = 0; k0 < K; k0 += 64) {
    if (k0 + 64 < K) {
      unsigned short* nA = As + (cur ^ 1) * 8192 + lbase;
      unsigned short* nB = Bs + (cur ^ 1) * 8192 + lbase;
      #pragma unroll
      for (int i = 0; i < 4; ++i) {
        glds16(gA + (k0 + 64) + (size_t)(i * 32) * lda, nA + i * 2048);
        glds16(gB + (k0 + 64) + (size_t)(i * 32) * ldb, nB + i * 2048);
      }
    }
    const char* cA = (const char*)(As + cur * 8192);
    const char* cB = (const char*)(Bs + cur * 8192);
    #pragma unroll
    for (int kk = 0; kk < 2; ++kk) {
      bf16x8 af[4], bfv[4];
      #pragma unroll
      for (int i = 0; i < 4; ++i) {
        const int ra = rw + i * 16 + fm;
        const int rb = cw + i * 16 + fm;
        af[i]  = *(const bf16x8*)(cA + ((((ra << 7) + (kk << 6) + (fq << 4))) ^ swz));
        bfv[i] = *(const bf16x8*)(cB + ((((rb << 7) + (kk << 6) + (fq << 4))) ^ swz));
      }
      #pragma unroll
      for (int mi = 0; mi < 4; ++mi)
        #pragma unroll
        for (int ni = 0; ni < 4; ++ni)
          acc[mi][ni] = __builtin_amdgcn_mfma_f32_16x16x32_bf16(af[mi], bfv[ni], acc[mi][ni], 0, 0, 0);
    }
    __syncthreads();
    cur ^= 1;
  }
}

// ---------------- small kernels ----------------

// cos/sin table packed as fp16 pairs: uint = (sin16<<16)|cos16. 4 MiB total.
// Also zeroes the 64 split-K ballot counters (once per launch).
__global__ __launch_bounds__(256) void k_csinit(unsigned int* __restrict__ cs,
                                                int* __restrict__ cnt) {
  int idx = blockIdx.x * 256 + threadIdx.x;
  if (idx < 64) cnt[idx] = 0;
  int t = idx >> 11, p = idx & (NPAIR - 1);
  const float INV2PI = 0.15915494309189535f;
  const float TWOPI = 6.283185307179586f;
  float f = exp2f(-16.0f * (float)(2 * p) / (float)NN) * INV2PI;
  float ph = fmodf((float)t * f, 1.0f) * TWOPI;
  float s, c;
  sincosf(ph, &s, &c);
  __half hc = __float2half_rn(c), hs = __float2half_rn(s);
  unsigned short uc = *reinterpret_cast<unsigned short*>(&hc);
  unsigned short us_ = *reinterpret_cast<unsigned short*>(&hs);
  cs[idx] = ((unsigned int)us_ << 16) | uc;
}

// fused transpose+cast for enc, encv, dec — one dispatch (3072 blocks)
__global__ __launch_bounds__(256) void k_tcast3(const float* __restrict__ enc,
                                                const float* __restrict__ encv,
                                                const float* __restrict__ dec,
                                                unsigned short* __restrict__ encT,
                                                unsigned short* __restrict__ encvT,
                                                unsigned short* __restrict__ decT) {
  __shared__ float tile[64][65];
  const int lin = blockIdx.x;
  const float* in;
  unsigned short* out;
  int R, C, bx, by, bz;
  if (lin < 2048) {
    const int which = lin >> 10;
    in = which ? encv : enc; out = which ? encvT : encT; R = DD; C = NN;
    const int r = lin & 1023;          // grid was (64, 4, 4)
    bx = r & 63; by = (r >> 6) & 3; bz = r >> 8;
  } else {
    in = dec; out = decT; R = NN; C = DD;
    const int r = lin - 2048;          // grid was (4, 64, 4)
    bx = r & 3; by = (r >> 2) & 63; bz = r >> 8;
  }
  const size_t zoff = (size_t)bz * R * C;
  const int r0 = by * 64, c0 = bx * 64;
  const int cl = threadIdx.x & 63, r4 = threadIdx.x >> 6;
  #pragma unroll 4
  for (int i = 0; i < 16; ++i) {
    int rl = r4 * 16 + i;
    tile[rl][cl] = in[zoff + (size_t)(r0 + rl) * C + c0 + cl];
  }
  __syncthreads();
  #pragma unroll 4
  for (int i = 0; i < 16; ++i) {
    int ccl = r4 * 16 + i;
    out[zoff + (size_t)(c0 + ccl) * R + r0 + cl] = f2bf(tile[cl][ccl]);
  }
}

// x[b,t,:] = LN(embed[ids]); emits f32 x, bf16 xbf, bf16 xT
__global__ __launch_bounds__(256) void k_embed_ln(const int* __restrict__ idw,
                                                  const float* __restrict__ tbl,
                                                  float* __restrict__ x,
                                                  unsigned short* __restrict__ xbf,
                                                  unsigned short* __restrict__ xTbf) {
  __shared__ int s_id;
  int row = blockIdx.x, tid = threadIdx.x;
  if (tid == 0) {
    bool is64 = true;
    for (int i = 1; i < 64; i += 2)
      if (idw[i] != 0) { is64 = false; break; }
    s_id = is64 ? idw[2 * row] : idw[row];
  }
  __syncthreads();
  int id = s_id;
  float v = tbl[(size_t)id * DD + tid];
  float mu = block_sum_256(v) * (1.0f / DD);
  float d = v - mu;
  float var = block_sum_256(d * d) * (1.0f / DD);
  float r = d * rsqrtf(var + 1e-5f);
  x[(size_t)row * DD + tid] = r;
  unsigned short rb = f2bf(r);
  xbf[(size_t)row * DD + tid] = rb;
  int b = row >> 9, t = row & 511;
  xTbf[((size_t)b * DD + tid) * TT + t] = rb;
}

// ---------------- GEMM kernels ----------------

// xsp = bf16(relu(x @ enc[h])); qr = bf16(rope(relu)).
// Flat grid 1024, XCD-pinned per bh. Dbuf w32 k-loop (1 barrier/step) +
// barrier-free per-wave transposed epilogue; fp16 cs table.
__global__ __launch_bounds__(256) void k_enc(const unsigned short* __restrict__ xbf,
                                             const unsigned short* __restrict__ encT,
                                             const unsigned int* __restrict__ csh,
                                             unsigned short* __restrict__ xsp,
                                             unsigned short* __restrict__ qr) {
  __shared__ unsigned short smem[32768];   // 64 KiB: As dbuf(32K) + Bs dbuf(32K)
  unsigned short* As = smem;
  unsigned short* Bs = smem + 16384;
  float* smemf = (float*)smem;             // epilogue reuse
  const int tid = threadIdx.x;
  const int lin = blockIdx.x;
  const int bh = lin & 7, r0 = lin >> 3;
  const int b = bh >> 2, h = bh & 3;
  const int m0 = (r0 >> 5) * 128, n0 = (r0 & 31) * 128;
  f32x4 acc[2][8] = {};
  mfma_tile128_w32_dbuf(xbf + (size_t)b * TT * DD + (size_t)m0 * DD, DD,
                        encT + (size_t)h * NN * DD + (size_t)n0 * DD, DD, DD, acc, As, Bs);
  // k-loop ended with __syncthreads -> safe to reuse LDS per-wave
  const int lane = tid & 63, wave = tid >> 6;
  const int fm = lane & 15, fq = lane >> 4;
  float* Scw = smemf + wave * (16 * 132);
  const int rr4 = lane >> 4, c0 = (lane & 15) << 3;
  const size_t base = (size_t)bh * TT * NN;
  #pragma unroll
  for (int mi = 0; mi < 2; ++mi) {
    if (mi) asm volatile("s_waitcnt lgkmcnt(0)" ::: "memory");  // WAR vs prev reads
    #pragma unroll
    for (int ni = 0; ni < 8; ++ni)
      #pragma unroll
      for (int r = 0; r < 4; ++r)
        Scw[(fq * 4 + r) * 132 + ni * 16 + fm] = acc[mi][ni][r];
    asm volatile("s_waitcnt lgkmcnt(0)" ::: "memory");          // RAW: writes visible
    #pragma unroll
    for (int k = 0; k < 4; ++k) {
      const int rr = k * 4 + rr4;
      float v[8];
      *(float4*)&v[0] = *(const float4*)&Scw[rr * 132 + c0];
      *(float4*)&v[4] = *(const float4*)&Scw[rr * 132 + c0 + 4];
      const int t = m0 + wave * 32 + mi * 16 + rr;
      const int n = n0 + c0;
      #pragma unroll
      for (int j = 0; j < 8; ++j) v[j] = fmaxf(v[j], 0.0f);
      us8 o;
      #pragma unroll
      for (int j = 0; j < 8; ++j) o[j] = f2bf(v[j]);
      size_t off = base + (size_t)t * NN + n;
      *(us8*)(xsp + off) = o;
      const unsigned short* cp = (const unsigned short*)(csh + (size_t)t * NPAIR + (n >> 1));
      us8 cv = *(const us8*)cp;
      us8 q;
      #pragma unroll
      for (int j = 0; j < 4; ++j) {
        float c = h2f(cv[2 * j]), s = h2f(cv[2 * j + 1]);
        float ve = v[2 * j], vo = v[2 * j + 1];
        q[2 * j]     = f2bf(ve * c - vo * s);
        q[2 * j + 1] = f2bf(vo * c + ve * s);
      }
      *(us8*)(qr + off) = q;
    }
  }
}

// scores partials: scp[bh*4+kc] = qr[:,kc*1024:+1024] · qr^T chunk (f32)
// Flat grid 320; bh = xcd. Dbuf staging. Diagonal tiles bake the strict
// causal mask as zeros.
__global__ __launch_bounds__(256) void k_scores_part(const unsigned short* __restrict__ qr,
                                                     float* __restrict__ scp) {
  __shared__ float smemf[16384];         // 64 KiB: As(2x16K) + Bs(2x16K)
  unsigned short* As = (unsigned short*)smemf;
  unsigned short* Bs = As + 16384;
  const int lin = blockIdx.x;
  const int xcd = lin & 7, slot = lin >> 3;         // slot 0..39
  const int zg = slot / 10, p = slot - zg * 10;     // zg 0..3, p 0..9
  const int z = xcd * 4 + zg;                       // bh = xcd, kc = zg
  const int bh = z >> 2, kc = z & 3;
  const int mt = (p > 0) + (p > 2) + (p > 5);
  const int nt = p - mt * (mt + 1) / 2;
  const int m0 = mt * 128, n0 = nt * 128;
  const unsigned short* Q = qr + (size_t)bh * TT * NN + kc * 1024;
  f32x4 acc[4][4] = {};
  mfma_tile128_dbuf(Q + (size_t)m0 * NN, NN, Q + (size_t)n0 * NN, NN, 1024, acc, As, Bs);
  const int lane = threadIdx.x & 63, wave = threadIdx.x >> 6;
  const int fm = lane & 15, fq = lane >> 4;
  const int rw = (wave >> 1) << 6, cw = (wave & 1) << 6;
  float* C = scp + (size_t)z * TT * TT;
  const bool diag = (m0 == n0);
  #pragma unroll
  for (int ni = 0; ni < 4; ++ni) {
    int s = n0 + cw + ni * 16 + fm;
    #pragma unroll
    for (int mi = 0; mi < 4; ++mi) {
      int trow = m0 + rw + mi * 16 + (fq << 2);
      #pragma unroll
      for (int r = 0; r < 4; ++r) {
        float v = acc[mi][ni][r];
        if (diag && s >= trow + r) v = 0.0f;        // strict causal: keep s < t
        C[(size_t)(trow + r) * TT + s] = v;
      }
    }
  }
}

// ykv partials + FUSED last-block LN reduction (replaces k_ykv_red).
// Compact grid 160 = 8 bh x 20 (jp,ks) active pairs; bh = lin&7 keeps XCD
// pinning (scp[bh] + all contributors of a tile on one XCD -> L2-coherent
// with threadfence + device-scope atomic ballot). Winner block performs
// exactly the old k_ykv_red math (same slab order) for its 64 rows.
__global__ __launch_bounds__(256) void k_ykv_part(const float* __restrict__ scp,
                                                  const unsigned short* __restrict__ xTbf,
                                                  float* __restrict__ ykvp,
                                                  unsigned short* __restrict__ ykvbf,
                                                  int* __restrict__ cnt) {
  __shared__ unsigned short As[64][40];
  __shared__ unsigned short Bs[256][40];
  __shared__ int s_old;
  const int tid = threadIdx.x;
  const int lin = blockIdx.x;
  const int bh = lin & 7, p = lin >> 3;    // p 0..19
  int jp, ks;
  if (p < 2)       { jp = p;                ks = 0; }
  else if (p < 6)  { jp = 2 + ((p - 2) >> 1); ks = (p - 2) & 1; }
  else if (p < 12) { jp = 4 + (p - 6) / 3;  ks = (p - 6) % 3; }
  else             { jp = 6 + ((p - 12) >> 2); ks = (p - 12) & 3; }
  const int m0 = jp * 64, b = bh >> 2;
  const int need = (jp >> 1) + 1;          // active ks count for this tile
  float* C = ykvp + ((size_t)(bh * 4 + ks) * TT + m0) * DD;
  const int lane = tid & 63, wave = tid >> 6;
  const int srow = tid >> 2, sk = (tid & 3) << 3;
  const int fm = lane & 15, fq = lane >> 4;
  const int t = m0 + srow;
  const size_t abase0 = (size_t)(bh * 4) * TT * TT + (size_t)t * TT;
  const unsigned short* Brow = xTbf + ((size_t)b * DD + tid) * TT + ks * 128;
  f32x4 acc[16] = {};
  for (int k0 = 0; k0 < 128; k0 += 32) {
    const int s0 = ks * 128 + k0 + sk;
    const float* pp = scp + abase0 + s0;
    float sum[8];
    float4 u0 = *(const float4*)(pp);
    float4 u1 = *(const float4*)(pp + 4);
    sum[0] = u0.x; sum[1] = u0.y; sum[2] = u0.z; sum[3] = u0.w;
    sum[4] = u1.x; sum[5] = u1.y; sum[6] = u1.z; sum[7] = u1.w;
    #pragma unroll
    for (int kc = 1; kc < 4; ++kc) {
      float4 v0 = *(const float4*)(pp + (size_t)kc * TT * TT);
      float4 v1 = *(const float4*)(pp + (size_t)kc * TT * TT + 4);
      sum[0] += v0.x; sum[1] += v0.y; sum[2] += v0.z; sum[3] += v0.w;
      sum[4] += v1.x; sum[5] += v1.y; sum[6] += v1.z; sum[7] += v1.w;
    }
    us8 av;
    #pragma unroll
    for (int j = 0; j < 8; ++j) av[j] = f2bf(sum[j]);
    us8 bv0 = *(const us8*)(Brow + k0);
    us8 bv1 = *(const us8*)(Brow + k0 + 8);
    us8 bv2 = *(const us8*)(Brow + k0 + 16);
    us8 bv3 = *(const us8*)(Brow + k0 + 24);
    __syncthreads();
    *(us8*)(&As[srow][sk]) = av;
    *(us8*)(&Bs[tid][0]) = bv0;
    *(us8*)(&Bs[tid][8]) = bv1;
    *(us8*)(&Bs[tid][16]) = bv2;
    *(us8*)(&Bs[tid][24]) = bv3;
    __syncthreads();
    bf16x8 a = *(const bf16x8*)(&As[wave * 16 + fm][fq << 3]);
    #pragma unroll
    for (int ni = 0; ni < 16; ++ni) {
      bf16x8 bfr = *(const bf16x8*)(&Bs[ni * 16 + fm][fq << 3]);
      acc[ni] = __builtin_amdgcn_mfma_f32_16x16x32_bf16(a, bfr, acc[ni], 0, 0, 0);
    }
  }
  const int trow = wave * 16 + (fq << 2);
  #pragma unroll
  for (int ni = 0; ni < 16; ++ni)
    #pragma unroll
    for (int r = 0; r < 4; ++r)
      C[(size_t)(trow + r) * DD + ni * 16 + fm] = acc[ni][r];
  // ---- last-block ballot: contributors all on XCD `bh` (lin&7 pinning)
  __threadfence();                         // release: C writes visible
  __syncthreads();                         // all threads' stores issued+fenced
  const int tile = bh * 8 + jp;
  if (tid == 0) s_old = atomicAdd(&cnt[tile], 1);
  __syncthreads();
  if (s_old != need - 1) return;
  __threadfence();                         // acquire side
  if (tid == 0) cnt[tile] = 0;             // self-reset for next layer
  // ---- fused LN reduction: identical math/order to old k_ykv_red
  const int d0 = lane << 2;
  for (int it = 0; it < 16; ++it) {
    const int t2 = m0 + it * 4 + wave;
    const size_t base2 = ((size_t)(bh * 4) * TT + t2) * DD + d0;
    f32x4 v = *(const f32x4*)(ykvp + base2);
    if (need > 1) v += *(const f32x4*)(ykvp + base2 + (size_t)TT * DD);
    if (need > 2) v += *(const f32x4*)(ykvp + base2 + (size_t)2 * TT * DD);
    if (need > 3) v += *(const f32x4*)(ykvp + base2 + (size_t)3 * TT * DD);
    float mu = wave_sum64(v.x + v.y + v.z + v.w) * (1.0f / DD);
    f32x4 d = v - mu;
    float var = wave_sum64(d.x * d.x + d.y * d.y + d.z * d.z + d.w * d.w) * (1.0f / DD);
    f32x4 r = d * rsqrtf(var + 1e-5f);
    us4 rb;
    #pragma unroll
    for (int j = 0; j < 4; ++j) rb[j] = f2bf(r[j]);
    *(us4*)(ykvbf + ((size_t)bh * TT + t2) * DD + d0) = rb;
  }
}

// xy_bf = xsp_bf * relu(ykv_bf @ encv[h]) — dbuf w32, barrier-free epilogue
__global__ __launch_bounds__(256) void k_ysp_xy(const unsigned short* __restrict__ ykvbf,
                                                const unsigned short* __restrict__ encvT,
                                                const unsigned short* __restrict__ xsp,
                                                unsigned short* __restrict__ xy) {
  __shared__ unsigned short smem[32768];   // 64 KiB dbuf
  unsigned short* As = smem;
  unsigned short* Bs = smem + 16384;
  float* smemf = (float*)smem;
  const int tid = threadIdx.x;
  const int lin = blockIdx.x;
  const int bh = lin & 7, r0 = lin >> 3;
  const int h = bh & 3;
  const int m0 = (r0 >> 5) * 128, n0 = (r0 & 31) * 128;
  f32x4 acc[2][8] = {};
  mfma_tile128_w32_dbuf(ykvbf + (size_t)bh * TT * DD + (size_t)m0 * DD, DD,
                        encvT + (size_t)h * NN * DD + (size_t)n0 * DD, DD, DD, acc, As, Bs);
  const int lane = tid & 63, wave = tid >> 6;
  const int fm = lane & 15, fq = lane >> 4;
  float* Scw = smemf + wave * (16 * 132);
  const int rr4 = lane >> 4, c0 = (lane & 15) << 3;
  const size_t base = (size_t)bh * TT * NN;
  #pragma unroll
  for (int mi = 0; mi < 2; ++mi) {
    if (mi) asm volatile("s_waitcnt lgkmcnt(0)" ::: "memory");
    #pragma unroll
    for (int ni = 0; ni < 8; ++ni)
      #pragma unroll
      for (int r = 0; r < 4; ++r)
        Scw[(fq * 4 + r) * 132 + ni * 16 + fm] = acc[mi][ni][r];
    asm volatile("s_waitcnt lgkmcnt(0)" ::: "memory");
    #pragma unroll
    for (int k = 0; k < 4; ++k) {
      const int rr = k * 4 + rr4;
      float v[8];
      *(float4*)&v[0] = *(const float4*)&Scw[rr * 132 + c0];
      *(float4*)&v[4] = *(const float4*)&Scw[rr * 132 + c0 + 4];
      const int t = m0 + wave * 32 + mi * 16 + rr;
      const int n = n0 + c0;
      size_t off = base + (size_t)t * NN + n;
      us8 x0 = *(const us8*)(xsp + off);
      us8 o;
      #pragma unroll
      for (int j = 0; j < 8; ++j)
        o[j] = f2bf(bf2f(x0[j]) * fmaxf(v[j], 0.0f));
      *(us8*)(xy + off) = o;
    }
  }
}

// ym32[bh*4+ks] = xy_bf chunk @ dec[h] chunk  (K-split 4 -> 256 blocks)
// Dbuf staging; bh = xcd (xy[bh] 4MB + decT[h] 2.1MB L2-pinned per XCD).
__global__ __launch_bounds__(256) void k_ymlp(const unsigned short* __restrict__ xy,
                                              const unsigned short* __restrict__ decT,
                                              float* __restrict__ ym32) {
  __shared__ float smemf[16384];         // 64 KiB dbuf
  unsigned short* As = (unsigned short*)smemf;
  unsigned short* Bs = As + 16384;
  const int lin = blockIdx.x;
  const int bh = lin & 7, r0 = lin >> 3;            // r0 0..31
  const int ks = r0 >> 3, tile = r0 & 7;
  const int z = bh * 4 + ks, h = bh & 3;
  const int m0 = (tile & 3) * 128, n0 = (tile >> 2) * 128;
  f32x4 acc[4][4] = {};
  mfma_tile128_dbuf(xy + (size_t)bh * TT * NN + (size_t)m0 * NN + ks * 1024, NN,
                    decT + (size_t)h * DD * NN + (size_t)n0 * NN + ks * 1024, NN,
                    1024, acc, As, Bs);
  const int lane = threadIdx.x & 63, wave = threadIdx.x >> 6;
  const int fm = lane & 15, fq = lane >> 4;
  const int rw = (wave >> 1) << 6, cw = (wave & 1) << 6;
  float* C = ym32 + (size_t)z * TT * DD;
  #pragma unroll
  for (int ni = 0; ni < 4; ++ni) {
    int d = n0 + cw + ni * 16 + fm;
    #pragma unroll
    for (int mi = 0; mi < 4; ++mi) {
      int trow = m0 + rw + mi * 16 + (fq << 2);
      #pragma unroll
      for (int r = 0; r < 4; ++r)
        C[(size_t)(trow + r) * DD + d] = acc[mi][ni][r];
    }
  }
}

// x = LN(x + LN(sum of 16 partials)); emits f32 x, bf16 xbf, bf16 xT — one row/wave
__global__ __launch_bounds__(256) void k_ln2(float* __restrict__ x,
                                             const float* __restrict__ ym32,
                                             unsigned short* __restrict__ xbf,
                                             unsigned short* __restrict__ xTbf) {
  int row = blockIdx.x * 4 + (threadIdx.x >> 6);
  int lane = threadIdx.x & 63;
  int b = row >> 9, t = row & 511;
  int d0 = lane << 2;
  f32x4 y = {0.0f, 0.0f, 0.0f, 0.0f};
  size_t rbase = (size_t)t * DD + d0;
  #pragma unroll
  for (int p = 0; p < 16; ++p)
    y += *(const f32x4*)(ym32 + (size_t)(b * 16 + p) * TT * DD + rbase);
  float mu = wave_sum64(y.x + y.y + y.z + y.w) * (1.0f / DD);
  f32x4 d = y - mu;
  float var = wave_sum64(d.x * d.x + d.y * d.y + d.z * d.z + d.w * d.w) * (1.0f / DD);
  f32x4 ly = d * rsqrtf(var + 1e-5f);
  f32x4 xv = *(const f32x4*)(x + (size_t)row * DD + d0) + ly;
  float mu2 = wave_sum64(xv.x + xv.y + xv.z + xv.w) * (1.0f / DD);
  f32x4 d2 = xv - mu2;
  float var2 = wave_sum64(d2.x * d2.x + d2.y * d2.y + d2.z * d2.z + d2.w * d2.w) * (1.0f / DD);
  f32x4 r = d2 * rsqrtf(var2 + 1e-5f);
  *(f32x4*)(x + (size_t)row * DD + d0) = r;
  us4 rb;
  #pragma unroll
  for (int j = 0; j < 4; ++j) rb[j] = f2bf(r[j]);
  *(us4*)(xbf + (size_t)row * DD + d0) = rb;
  #pragma unroll
  for (int j = 0; j < 4; ++j)
    xTbf[((size_t)b * DD + d0 + j) * TT + t] = rb[j];
}

// trace pass 1: partial column-sums of xy over 32-row t-slices, us8 loads.
__global__ __launch_bounds__(256) void k_trace_part(const unsigned short* __restrict__ xy,
                                                    float* __restrict__ part) {
  const int lin = blockIdx.x;              // 256 blocks = 8bh x 2nc x 16ts
  const int ts = lin & 15, nc = (lin >> 4) & 1, bh = lin >> 5;
  const int n0 = nc * 2048 + threadIdx.x * 8;
  const size_t base = (size_t)bh * TT * NN + n0;
  float acc[8];
  #pragma unroll
  for (int j = 0; j < 8; ++j) acc[j] = 0.0f;
  for (int t = ts * 32; t < ts * 32 + 32; ++t) {
    us8 v = *(const us8*)(xy + base + (size_t)t * NN);
    #pragma unroll
    for (int j = 0; j < 8; ++j) acc[j] += bf2f(v[j]);
  }
  float* o = part + (size_t)(bh * 16 + ts) * NN + n0;
  #pragma unroll
  for (int j = 0; j < 8; ++j) o[j] = acc[j];
}

// trace pass 2: reduce the 16 t-slices
__global__ __launch_bounds__(256) void k_trace_red(const float* __restrict__ part,
                                                   float* __restrict__ out) {
  int idx = blockIdx.x * 256 + threadIdx.x;   // 32768 outputs
  int bh = idx >> 12, n = idx & 4095;
  float s = 0.0f;
  #pragma unroll
  for (int ts = 0; ts < 16; ++ts)
    s += part[(size_t)(bh * 16 + ts) * NN + n];
  out[idx] = s * (1.0f / TT);
}

__global__ __launch_bounds__(256) void k_logits(const float* __restrict__ x,
                                                const float* __restrict__ W,
                                                float* __restrict__ out) {
  __shared__ float xs[DD];
  int row = blockIdx.x, tid = threadIdx.x;
  xs[tid] = x[(size_t)row * DD + tid];
  __syncthreads();
  float s = 0.0f;
  #pragma unroll 8
  for (int d = 0; d < DD; ++d) s = fmaf(xs[d], W[(size_t)d * VV + tid], s);
  out[(size_t)row * VV + tid] = s;
}

// embedding pass 1: 64 blocks (b x 32 t-chunks of 16), partials to ws
__global__ __launch_bounds__(256) void k_embed_part(const float* __restrict__ x,
                                                    float* __restrict__ part) {
  const int lin = blockIdx.x;              // 64 = 2b x 32tc
  const int tc = lin & 31, b = lin >> 5;
  const int d = threadIdx.x;
  float s = 0.0f;
  #pragma unroll
  for (int i = 0; i < 16; ++i)
    s += x[(size_t)(b * TT + tc * 16 + i) * DD + d];
  part[(size_t)lin * DD + d] = s;
}

// embedding pass 2: reduce the 32 t-chunks per b
__global__ __launch_bounds__(256) void k_embed_red(const float* __restrict__ part,
                                                   float* __restrict__ out) {
  int idx = blockIdx.x * 256 + threadIdx.x;   // 512 outputs
  int b = idx >> 8, d = idx & 255;
  float s = 0.0f;
  #pragma unroll
  for (int tc = 0; tc < 32; ++tc)
    s += part[(size_t)(b * 32 + tc) * DD + d];
  out[idx] = s * (1.0f / TT);
}

extern "C" void kernel_launch(void* const* d_in, const int* in_sizes, int n_in,
                              void* d_out, int out_size, void* d_ws, size_t ws_size,
                              hipStream_t stream) {
  const int*   ids  = (const int*)d_in[0];
  const float* tbl  = (const float*)d_in[1];
  const float* enc  = (const float*)d_in[2];
  const float* encv = (const float*)d_in[3];
  const float* dec  = (const float*)d_in[4];
  const float* lmh  = (const float*)d_in[5];

  // workspace layout (float units), ~184.5 MiB total
  float* ws   = (float*)d_ws;
  float* x    = ws;                                              //   262,144 f
  unsigned short* ykvbf = (unsigned short*)(x + 262144);         // 1,048,576 us
  float* ym32 = (float*)(ykvbf + 1048576);                       // 8,388,608 f (32 slabs used)
  unsigned short* xbf   = (unsigned short*)(ym32 + 8388608);     //   262,144 us
  unsigned short* xTbf  = xbf + 262144;                          //   262,144 us
  unsigned short* encT  = xTbf + 262144;                         // 4,194,304 us
  unsigned short* encvT = encT + 4194304;                        // 4,194,304 us
  unsigned short* decT  = encvT + 4194304;                       // 4,194,304 us
  unsigned short* xspbf = decT + 4194304;                        // 16,777,216 us
  unsigned short* qxybf = xspbf + 16777216;                      // 16,777,216 us
  unsigned int* cs = (unsigned int*)(qxybf + 16777216);          // 1,048,576 uint (4 MiB fp16 pairs)
  float* scp  = (float*)(cs + 2097152);                          // 8,388,608 f (32 MiB)
  float* ykvp = scp + 8388608;                                   // 4,194,304 f (16 MiB)
  int*   cnt  = (int*)(ykvp + 4194304);                          //        64 ints (ballots)
  // final-phase scratch (reuses scp region, free after last layer):
  float* tpart = scp;                                            // 524,288 f (trace partials)
  float* epart = scp + 524288;                                   // 16,384 f (embed partials)

  float* out_logits = (float*)d_out;
  float* out_embed  = out_logits + (size_t)BB * TT * VV;
  float* out_trace  = out_embed + (size_t)BB * DD;

  k_csinit<<<(TT * NPAIR) / 256, 256, 0, stream>>>(cs, cnt);
  k_tcast3<<<3072, 256, 0, stream>>>(enc, encv, dec, encT, encvT, decT);

  k_embed_ln<<<BB * TT, 256, 0, stream>>>(ids, tbl, x, xbf, xTbf);
  for (int l = 0; l < NLAYER; ++l) {
    k_enc        <<<1024, 256, 0, stream>>>(xbf, encT, cs, xspbf, qxybf);
    k_scores_part<<<320, 256, 0, stream>>>(qxybf, scp);
    k_ykv_part   <<<160, 256, 0, stream>>>(scp, xTbf, ykvp, ykvbf, cnt);
    k_ysp_xy     <<<1024, 256, 0, stream>>>(ykvbf, encvT, xspbf, qxybf);
    k_ymlp       <<<256, 256, 0, stream>>>(qxybf, decT, ym32);
    k_ln2        <<<BB * TT / 4, 256, 0, stream>>>(x, ym32, xbf, xTbf);
  }
  k_trace_part<<<256, 256, 0, stream>>>(qxybf, tpart);
  k_trace_red <<<128, 256, 0, stream>>>(tpart, out_trace);
  k_logits    <<<BB * TT, 256, 0, stream>>>(x, lmh, out_logits);
  k_embed_part<<<64, 256, 0, stream>>>(x, epart);
  k_embed_red <<<2, 256, 0, stream>>>(epart, out_embed);
}

// Round 12
// 690.526 us; speedup vs baseline: 1.4229x; 1.4229x over previous
//
#include <hip/hip_runtime.h>
#include <hip/hip_bf16.h>
#include <hip/hip_fp16.h>

#define TT 512
#define DD 256
#define NH 4
#define NN 4096
#define VV 256
#define NLAYER 6
#define BB 2
#define BH (BB * NH)
#define NPAIR 2048

typedef __attribute__((ext_vector_type(8))) short bf16x8;
typedef __attribute__((ext_vector_type(4))) float f32x4;
typedef __attribute__((ext_vector_type(8))) unsigned short us8;
typedef __attribute__((ext_vector_type(4))) unsigned short us4;

#define AS1 __attribute__((address_space(1)))
#define AS3 __attribute__((address_space(3)))

__device__ __forceinline__ void glds16(const unsigned short* g, unsigned short* l) {
  __builtin_amdgcn_global_load_lds((const AS1 void*)g, (AS3 void*)l, 16, 0, 0);
}

__device__ __forceinline__ unsigned short f2bf(float f) {
  unsigned int u = __float_as_uint(f);
  return (unsigned short)((u + 0x7FFFu + ((u >> 16) & 1u)) >> 16);
}
__device__ __forceinline__ float bf2f(unsigned short h) {
  return __uint_as_float((unsigned int)h << 16);
}
__device__ __forceinline__ float h2f(unsigned short h) {
  __half x = *reinterpret_cast<__half*>(&h);
  return __half2float(x);
}

// ---------------- block-wide sum over 256 threads ----------------
__device__ __forceinline__ float block_sum_256(float v) {
  __shared__ float s[4];
  #pragma unroll
  for (int o = 32; o > 0; o >>= 1) v += __shfl_down(v, o);
  int lane = threadIdx.x & 63, wid = threadIdx.x >> 6;
  if (lane == 0) s[wid] = v;
  __syncthreads();
  float r = s[0] + s[1] + s[2] + s[3];
  __syncthreads();
  return r;
}

// ---------------- wave-local sum over 64 lanes (no barriers) -------------
__device__ __forceinline__ float wave_sum64(float v) {
  #pragma unroll
  for (int o = 32; o > 0; o >>= 1) v += __shfl_xor(v, o);
  return v;
}

// ---- 128x128 MFMA tile, BK=64 DOUBLE-BUFFERED, WAVE-ROW mapping (R6-proven):
//      wave w owns output rows [w*32,w*32+32), all 128 cols -> acc[2][8].
//      One __syncthreads per k-step; next tile's glds issued before compute.
//      K order ascending 32-slices -> bit-identical accumulation.
__device__ __forceinline__ void mfma_tile128_w32_dbuf(const unsigned short* __restrict__ A, int lda,
                                                      const unsigned short* __restrict__ B, int ldb,
                                                      int K, f32x4 acc[2][8],
                                                      unsigned short* As, unsigned short* Bs) {
  const int tid = threadIdx.x;
  const int lane = tid & 63, wave = tid >> 6;
  const int fm = lane & 15, fq = lane >> 4;
  const int wrow = wave << 5;
  const int lrow = lane >> 3;                        // row within 8-row group
  const int scol = (((lane & 7) ^ lrow) << 3);       // pre-swizzled source col (elems)
  const unsigned short* gA = A + (size_t)(wave * 8 + lrow) * lda + scol;
  const unsigned short* gB = B + (size_t)(wave * 8 + lrow) * ldb + scol;
  const int lbase = wave * 512;
  const int swz = (fm & 7) << 4;                     // read-side XOR (bits 4..6)
  #pragma unroll
  for (int i = 0; i < 4; ++i) {
    glds16(gA + (size_t)(i * 32) * lda, As + lbase + i * 2048);
    glds16(gB + (size_t)(i * 32) * ldb, Bs + lbase + i * 2048);
  }
  __syncthreads();
  int cur = 0;
  for (int k0 = 0; k0 < K; k0 += 64) {
    if (k0 + 64 < K) {
      unsigned short* nA = As + (cur ^ 1) * 8192 + lbase;
      unsigned short* nB = Bs + (cur ^ 1) * 8192 + lbase;
      #pragma unroll
      for (int i = 0; i < 4; ++i) {
        glds16(gA + (k0 + 64) + (size_t)(i * 32) * lda, nA + i * 2048);
        glds16(gB + (k0 + 64) + (size_t)(i * 32) * ldb, nB + i * 2048);
      }
    }
    const char* cA = (const char*)(As + cur * 8192);
    const char* cB = (const char*)(Bs + cur * 8192);
    #pragma unroll
    for (int kk = 0; kk < 2; ++kk) {
      bf16x8 af[2], bfv[8];
      #pragma unroll
      for (int i = 0; i < 2; ++i) {
        const int ra = wrow + i * 16 + fm;
        af[i] = *(const bf16x8*)(cA + ((((ra << 7) + (kk << 6) + (fq << 4))) ^ swz));
      }
      #pragma unroll
      for (int i = 0; i < 8; ++i) {
        const int rb = i * 16 + fm;
        bfv[i] = *(const bf16x8*)(cB + ((((rb << 7) + (kk << 6) + (fq << 4))) ^ swz));
      }
      #pragma unroll
      for (int mi = 0; mi < 2; ++mi)
        #pragma unroll
        for (int ni = 0; ni < 8; ++ni)
          acc[mi][ni] = __builtin_amdgcn_mfma_f32_16x16x32_bf16(af[mi], bfv[ni], acc[mi][ni], 0, 0, 0);
    }
    __syncthreads();   // drains next-stage glds; protects buffer reuse
    cur ^= 1;
  }
}
// C/D: row = m0 + wave*32 + mi*16 + fq*4 + r ; col = n0 + ni*16 + fm

// ---- 128x128 MFMA tile, BK=64 DOUBLE-BUFFERED, 4x4 wave-quadrant mapping.
__device__ __forceinline__ void mfma_tile128_dbuf(const unsigned short* __restrict__ A, int lda,
                                                  const unsigned short* __restrict__ B, int ldb,
                                                  int K, f32x4 acc[4][4],
                                                  unsigned short* As, unsigned short* Bs) {
  const int tid = threadIdx.x;
  const int lane = tid & 63, wave = tid >> 6;
  const int fm = lane & 15, fq = lane >> 4;
  const int rw = (wave >> 1) << 6, cw = (wave & 1) << 6;
  const int lrow = lane >> 3;
  const int scol = (((lane & 7) ^ lrow) << 3);
  const unsigned short* gA = A + (size_t)(wave * 8 + lrow) * lda + scol;
  const unsigned short* gB = B + (size_t)(wave * 8 + lrow) * ldb + scol;
  const int lbase = wave * 512;
  const int swz = (fm & 7) << 4;
  #pragma unroll
  for (int i = 0; i < 4; ++i) {
    glds16(gA + (size_t)(i * 32) * lda, As + lbase + i * 2048);
    glds16(gB + (size_t)(i * 32) * ldb, Bs + lbase + i * 2048);
  }
  __syncthreads();
  int cur = 0;
  for (int k0 = 0; k0 < K; k0 += 64) {
    if (k0 + 64 < K) {
      unsigned short* nA = As + (cur ^ 1) * 8192 + lbase;
      unsigned short* nB = Bs + (cur ^ 1) * 8192 + lbase;
      #pragma unroll
      for (int i = 0; i < 4; ++i) {
        glds16(gA + (k0 + 64) + (size_t)(i * 32) * lda, nA + i * 2048);
        glds16(gB + (k0 + 64) + (size_t)(i * 32) * ldb, nB + i * 2048);
      }
    }
    const char* cA = (const char*)(As + cur * 8192);
    const char* cB = (const char*)(Bs + cur * 8192);
    #pragma unroll
    for (int kk = 0; kk < 2; ++kk) {
      bf16x8 af[4], bfv[4];
      #pragma unroll
      for (int i = 0; i < 4; ++i) {
        const int ra = rw + i * 16 + fm;
        const int rb = cw + i * 16 + fm;
        af[i]  = *(const bf16x8*)(cA + ((((ra << 7) + (kk << 6) + (fq << 4))) ^ swz));
        bfv[i] = *(const bf16x8*)(cB + ((((rb << 7) + (kk << 6) + (fq << 4))) ^ swz));
      }
      #pragma unroll
      for (int mi = 0; mi < 4; ++mi)
        #pragma unroll
        for (int ni = 0; ni < 4; ++ni)
          acc[mi][ni] = __builtin_amdgcn_mfma_f32_16x16x32_bf16(af[mi], bfv[ni], acc[mi][ni], 0, 0, 0);
    }
    __syncthreads();
    cur ^= 1;
  }
}

// ---------------- fused startup: csinit U tcast3 U embed_ln ----------------
// Independent sub-kernels (no data deps) -> one dispatch, block-uniform branch.
__global__ __launch_bounds__(256) void k_startup(unsigned int* __restrict__ cs,
                                                 const float* __restrict__ enc,
                                                 const float* __restrict__ encv,
                                                 const float* __restrict__ dec,
                                                 unsigned short* __restrict__ encT,
                                                 unsigned short* __restrict__ encvT,
                                                 unsigned short* __restrict__ decT,
                                                 const int* __restrict__ idw,
                                                 const float* __restrict__ tbl,
                                                 float* __restrict__ x,
                                                 unsigned short* __restrict__ xbf,
                                                 unsigned short* __restrict__ xTbf) {
  __shared__ float tile[64][65];
  const int blk = blockIdx.x;
  const int tid = threadIdx.x;
  if (blk < 4096) {
    // ---- csinit (grid 4096)
    int idx = blk * 256 + tid;
    int t = idx >> 11, p = idx & (NPAIR - 1);
    const float INV2PI = 0.15915494309189535f;
    const float TWOPI = 6.283185307179586f;
    float f = exp2f(-16.0f * (float)(2 * p) / (float)NN) * INV2PI;
    float ph = fmodf((float)t * f, 1.0f) * TWOPI;
    float s, c;
    sincosf(ph, &s, &c);
    __half hc = __float2half_rn(c), hs = __float2half_rn(s);
    unsigned short uc = *reinterpret_cast<unsigned short*>(&hc);
    unsigned short us_ = *reinterpret_cast<unsigned short*>(&hs);
    cs[idx] = ((unsigned int)us_ << 16) | uc;
  } else if (blk < 7168) {
    // ---- tcast3 (grid 3072)
    const int lin = blk - 4096;
    const float* in;
    unsigned short* out;
    int R, C, bx, by, bz;
    if (lin < 2048) {
      const int which = lin >> 10;
      in = which ? encv : enc; out = which ? encvT : encT; R = DD; C = NN;
      const int r = lin & 1023;
      bx = r & 63; by = (r >> 6) & 3; bz = r >> 8;
    } else {
      in = dec; out = decT; R = NN; C = DD;
      const int r = lin - 2048;
      bx = r & 3; by = (r >> 2) & 63; bz = r >> 8;
    }
    const size_t zoff = (size_t)bz * R * C;
    const int r0 = by * 64, c0 = bx * 64;
    const int cl = tid & 63, r4 = tid >> 6;
    #pragma unroll 4
    for (int i = 0; i < 16; ++i) {
      int rl = r4 * 16 + i;
      tile[rl][cl] = in[zoff + (size_t)(r0 + rl) * C + c0 + cl];
    }
    __syncthreads();
    #pragma unroll 4
    for (int i = 0; i < 16; ++i) {
      int ccl = r4 * 16 + i;
      out[zoff + (size_t)(c0 + ccl) * R + r0 + cl] = f2bf(tile[cl][ccl]);
    }
  } else {
    // ---- embed_ln (grid 1024)
    __shared__ int s_id;
    int row = blk - 7168;
    if (tid == 0) {
      bool is64 = true;
      for (int i = 1; i < 64; i += 2)
        if (idw[i] != 0) { is64 = false; break; }
      s_id = is64 ? idw[2 * row] : idw[row];
    }
    __syncthreads();
    int id = s_id;
    float v = tbl[(size_t)id * DD + tid];
    float mu = block_sum_256(v) * (1.0f / DD);
    float d = v - mu;
    float var = block_sum_256(d * d) * (1.0f / DD);
    float r = d * rsqrtf(var + 1e-5f);
    x[(size_t)row * DD + tid] = r;
    unsigned short rb = f2bf(r);
    xbf[(size_t)row * DD + tid] = rb;
    int b = row >> 9, t = row & 511;
    xTbf[((size_t)b * DD + tid) * TT + t] = rb;
  }
}

// ---------------- GEMM kernels ----------------

// xsp = bf16(relu(x @ enc[h])); qr = bf16(rope(relu)).
// Flat grid 1024, XCD-pinned per bh. Dbuf w32 k-loop (1 barrier/step) +
// barrier-free per-wave transposed epilogue; fp16 cs table.
__global__ __launch_bounds__(256) void k_enc(const unsigned short* __restrict__ xbf,
                                             const unsigned short* __restrict__ encT,
                                             const unsigned int* __restrict__ csh,
                                             unsigned short* __restrict__ xsp,
                                             unsigned short* __restrict__ qr) {
  __shared__ unsigned short smem[32768];   // 64 KiB: As dbuf(32K) + Bs dbuf(32K)
  unsigned short* As = smem;
  unsigned short* Bs = smem + 16384;
  float* smemf = (float*)smem;             // epilogue reuse
  const int tid = threadIdx.x;
  const int lin = blockIdx.x;
  const int bh = lin & 7, r0 = lin >> 3;
  const int b = bh >> 2, h = bh & 3;
  const int m0 = (r0 >> 5) * 128, n0 = (r0 & 31) * 128;
  f32x4 acc[2][8] = {};
  mfma_tile128_w32_dbuf(xbf + (size_t)b * TT * DD + (size_t)m0 * DD, DD,
                        encT + (size_t)h * NN * DD + (size_t)n0 * DD, DD, DD, acc, As, Bs);
  // k-loop ended with __syncthreads -> safe to reuse LDS per-wave
  const int lane = tid & 63, wave = tid >> 6;
  const int fm = lane & 15, fq = lane >> 4;
  float* Scw = smemf + wave * (16 * 132);
  const int rr4 = lane >> 4, c0 = (lane & 15) << 3;
  const size_t base = (size_t)bh * TT * NN;
  #pragma unroll
  for (int mi = 0; mi < 2; ++mi) {
    if (mi) asm volatile("s_waitcnt lgkmcnt(0)" ::: "memory");  // WAR vs prev reads
    #pragma unroll
    for (int ni = 0; ni < 8; ++ni)
      #pragma unroll
      for (int r = 0; r < 4; ++r)
        Scw[(fq * 4 + r) * 132 + ni * 16 + fm] = acc[mi][ni][r];
    asm volatile("s_waitcnt lgkmcnt(0)" ::: "memory");          // RAW: writes visible
    #pragma unroll
    for (int k = 0; k < 4; ++k) {
      const int rr = k * 4 + rr4;
      float v[8];
      *(float4*)&v[0] = *(const float4*)&Scw[rr * 132 + c0];
      *(float4*)&v[4] = *(const float4*)&Scw[rr * 132 + c0 + 4];
      const int t = m0 + wave * 32 + mi * 16 + rr;
      const int n = n0 + c0;
      #pragma unroll
      for (int j = 0; j < 8; ++j) v[j] = fmaxf(v[j], 0.0f);
      us8 o;
      #pragma unroll
      for (int j = 0; j < 8; ++j) o[j] = f2bf(v[j]);
      size_t off = base + (size_t)t * NN + n;
      *(us8*)(xsp + off) = o;
      const unsigned short* cp = (const unsigned short*)(csh + (size_t)t * NPAIR + (n >> 1));
      us8 cv = *(const us8*)cp;
      us8 q;
      #pragma unroll
      for (int j = 0; j < 4; ++j) {
        float c = h2f(cv[2 * j]), s = h2f(cv[2 * j + 1]);
        float ve = v[2 * j], vo = v[2 * j + 1];
        q[2 * j]     = f2bf(ve * c - vo * s);
        q[2 * j + 1] = f2bf(vo * c + ve * s);
      }
      *(us8*)(qr + off) = q;
    }
  }
}

// scores partials: scp[bh*4+kc] = qr[:,kc*1024:+1024] · qr^T chunk (f32)
// Flat grid 320; bh = xcd. Dbuf staging. Diagonal tiles bake the strict
// causal mask as zeros.
__global__ __launch_bounds__(256) void k_scores_part(const unsigned short* __restrict__ qr,
                                                     float* __restrict__ scp) {
  __shared__ float smemf[16384];         // 64 KiB: As(2x16K) + Bs(2x16K)
  unsigned short* As = (unsigned short*)smemf;
  unsigned short* Bs = As + 16384;
  const int lin = blockIdx.x;
  const int xcd = lin & 7, slot = lin >> 3;         // slot 0..39
  const int zg = slot / 10, p = slot - zg * 10;     // zg 0..3, p 0..9
  const int z = xcd * 4 + zg;                       // bh = xcd, kc = zg
  const int bh = z >> 2, kc = z & 3;
  const int mt = (p > 0) + (p > 2) + (p > 5);
  const int nt = p - mt * (mt + 1) / 2;
  const int m0 = mt * 128, n0 = nt * 128;
  const unsigned short* Q = qr + (size_t)bh * TT * NN + kc * 1024;
  f32x4 acc[4][4] = {};
  mfma_tile128_dbuf(Q + (size_t)m0 * NN, NN, Q + (size_t)n0 * NN, NN, 1024, acc, As, Bs);
  const int lane = threadIdx.x & 63, wave = threadIdx.x >> 6;
  const int fm = lane & 15, fq = lane >> 4;
  const int rw = (wave >> 1) << 6, cw = (wave & 1) << 6;
  float* C = scp + (size_t)z * TT * TT;
  const bool diag = (m0 == n0);
  #pragma unroll
  for (int ni = 0; ni < 4; ++ni) {
    int s = n0 + cw + ni * 16 + fm;
    #pragma unroll
    for (int mi = 0; mi < 4; ++mi) {
      int trow = m0 + rw + mi * 16 + (fq << 2);
      #pragma unroll
      for (int r = 0; r < 4; ++r) {
        float v = acc[mi][ni][r];
        if (diag && s >= trow + r) v = 0.0f;        // strict causal: keep s < t
        C[(size_t)(trow + r) * TT + s] = v;
      }
    }
  }
}

// ykv partials over s-chunks: ykvp[bh*4+ks] = scp-sum[:, ks*128:+128] @ x
// Mask baked into scp. Flat grid 256: xcd = bh (scp[bh] L2-resident).
// [R6/R10-proven version]
__global__ __launch_bounds__(256) void k_ykv_part(const float* __restrict__ scp,
                                                  const unsigned short* __restrict__ xTbf,
                                                  float* __restrict__ ykvp) {
  __shared__ unsigned short As[64][40];
  __shared__ unsigned short Bs[256][40];
  const int tid = threadIdx.x;
  const int lin = blockIdx.x;
  const int bh = lin & 7, r0 = lin >> 3;
  const int m0 = (r0 & 7) * 64, ks = r0 >> 3, b = bh >> 2;
  if (ks * 128 >= m0 + 64) return;   // whole s-chunk masked: slab never read
  float* C = ykvp + ((size_t)(bh * 4 + ks) * TT + m0) * DD;
  const int lane = tid & 63, wave = tid >> 6;
  const int srow = tid >> 2, sk = (tid & 3) << 3;
  const int fm = lane & 15, fq = lane >> 4;
  const int t = m0 + srow;
  const size_t abase0 = (size_t)(bh * 4) * TT * TT + (size_t)t * TT;
  const unsigned short* Brow = xTbf + ((size_t)b * DD + tid) * TT + ks * 128;
  f32x4 acc[16] = {};
  for (int k0 = 0; k0 < 128; k0 += 32) {
    const int s0 = ks * 128 + k0 + sk;
    const float* p = scp + abase0 + s0;
    float sum[8];
    float4 u0 = *(const float4*)(p);
    float4 u1 = *(const float4*)(p + 4);
    sum[0] = u0.x; sum[1] = u0.y; sum[2] = u0.z; sum[3] = u0.w;
    sum[4] = u1.x; sum[5] = u1.y; sum[6] = u1.z; sum[7] = u1.w;
    #pragma unroll
    for (int kc = 1; kc < 4; ++kc) {
      float4 v0 = *(const float4*)(p + (size_t)kc * TT * TT);
      float4 v1 = *(const float4*)(p + (size_t)kc * TT * TT + 4);
      sum[0] += v0.x; sum[1] += v0.y; sum[2] += v0.z; sum[3] += v0.w;
      sum[4] += v1.x; sum[5] += v1.y; sum[6] += v1.z; sum[7] += v1.w;
    }
    us8 av;
    #pragma unroll
    for (int j = 0; j < 8; ++j) av[j] = f2bf(sum[j]);
    us8 bv0 = *(const us8*)(Brow + k0);
    us8 bv1 = *(const us8*)(Brow + k0 + 8);
    us8 bv2 = *(const us8*)(Brow + k0 + 16);
    us8 bv3 = *(const us8*)(Brow + k0 + 24);
    __syncthreads();
    *(us8*)(&As[srow][sk]) = av;
    *(us8*)(&Bs[tid][0]) = bv0;
    *(us8*)(&Bs[tid][8]) = bv1;
    *(us8*)(&Bs[tid][16]) = bv2;
    *(us8*)(&Bs[tid][24]) = bv3;
    __syncthreads();
    bf16x8 a = *(const bf16x8*)(&As[wave * 16 + fm][fq << 3]);
    #pragma unroll
    for (int ni = 0; ni < 16; ++ni) {
      bf16x8 bfr = *(const bf16x8*)(&Bs[ni * 16 + fm][fq << 3]);
      acc[ni] = __builtin_amdgcn_mfma_f32_16x16x32_bf16(a, bfr, acc[ni], 0, 0, 0);
    }
  }
  const int trow = wave * 16 + (fq << 2);
  #pragma unroll
  for (int ni = 0; ni < 16; ++ni)
    #pragma unroll
    for (int r = 0; r < 4; ++r)
      C[(size_t)(trow + r) * DD + ni * 16 + fm] = acc[ni][r];
}

// ykvbf = bf16(LN(sum of ACTIVE ykv partials)) — one row per wave, no barriers.
__global__ __launch_bounds__(256) void k_ykv_red(const float* __restrict__ ykvp,
                                                 unsigned short* __restrict__ ykvbf) {
  int row = blockIdx.x * 4 + (threadIdx.x >> 6);   // row = bh*TT + t
  int lane = threadIdx.x & 63;
  int bh = row >> 9, t = row & 511;
  int d0 = lane << 2;
  int nks = (t >> 7) + 1;
  size_t base = ((size_t)(bh * 4) * TT + t) * DD + d0;
  f32x4 v = *(const f32x4*)(ykvp + base);
  if (nks > 1) v += *(const f32x4*)(ykvp + base + (size_t)TT * DD);
  if (nks > 2) v += *(const f32x4*)(ykvp + base + (size_t)2 * TT * DD);
  if (nks > 3) v += *(const f32x4*)(ykvp + base + (size_t)3 * TT * DD);
  float mu = wave_sum64(v.x + v.y + v.z + v.w) * (1.0f / DD);
  f32x4 d = v - mu;
  float var = wave_sum64(d.x * d.x + d.y * d.y + d.z * d.z + d.w * d.w) * (1.0f / DD);
  f32x4 r = d * rsqrtf(var + 1e-5f);
  us4 rb;
  #pragma unroll
  for (int j = 0; j < 4; ++j) rb[j] = f2bf(r[j]);
  *(us4*)(ykvbf + (size_t)row * DD + d0) = rb;
}

// xy_bf = xsp_bf * relu(ykv_bf @ encv[h]) — dbuf w32, barrier-free epilogue
__global__ __launch_bounds__(256) void k_ysp_xy(const unsigned short* __restrict__ ykvbf,
                                                const unsigned short* __restrict__ encvT,
                                                const unsigned short* __restrict__ xsp,
                                                unsigned short* __restrict__ xy) {
  __shared__ unsigned short smem[32768];   // 64 KiB dbuf
  unsigned short* As = smem;
  unsigned short* Bs = smem + 16384;
  float* smemf = (float*)smem;
  const int tid = threadIdx.x;
  const int lin = blockIdx.x;
  const int bh = lin & 7, r0 = lin >> 3;
  const int h = bh & 3;
  const int m0 = (r0 >> 5) * 128, n0 = (r0 & 31) * 128;
  f32x4 acc[2][8] = {};
  mfma_tile128_w32_dbuf(ykvbf + (size_t)bh * TT * DD + (size_t)m0 * DD, DD,
                        encvT + (size_t)h * NN * DD + (size_t)n0 * DD, DD, DD, acc, As, Bs);
  const int lane = tid & 63, wave = tid >> 6;
  const int fm = lane & 15, fq = lane >> 4;
  float* Scw = smemf + wave * (16 * 132);
  const int rr4 = lane >> 4, c0 = (lane & 15) << 3;
  const size_t base = (size_t)bh * TT * NN;
  #pragma unroll
  for (int mi = 0; mi < 2; ++mi) {
    if (mi) asm volatile("s_waitcnt lgkmcnt(0)" ::: "memory");
    #pragma unroll
    for (int ni = 0; ni < 8; ++ni)
      #pragma unroll
      for (int r = 0; r < 4; ++r)
        Scw[(fq * 4 + r) * 132 + ni * 16 + fm] = acc[mi][ni][r];
    asm volatile("s_waitcnt lgkmcnt(0)" ::: "memory");
    #pragma unroll
    for (int k = 0; k < 4; ++k) {
      const int rr = k * 4 + rr4;
      float v[8];
      *(float4*)&v[0] = *(const float4*)&Scw[rr * 132 + c0];
      *(float4*)&v[4] = *(const float4*)&Scw[rr * 132 + c0 + 4];
      const int t = m0 + wave * 32 + mi * 16 + rr;
      const int n = n0 + c0;
      size_t off = base + (size_t)t * NN + n;
      us8 x0 = *(const us8*)(xsp + off);
      us8 o;
      #pragma unroll
      for (int j = 0; j < 8; ++j)
        o[j] = f2bf(bf2f(x0[j]) * fmaxf(v[j], 0.0f));
      *(us8*)(xy + off) = o;
    }
  }
}

// ym32[bh*4+ks] = xy_bf chunk @ dec[h] chunk  (K-split 4 -> 256 blocks)
// Dbuf staging; bh = xcd (xy[bh] 4MB + decT[h] 2.1MB L2-pinned per XCD).
__global__ __launch_bounds__(256) void k_ymlp(const unsigned short* __restrict__ xy,
                                              const unsigned short* __restrict__ decT,
                                              float* __restrict__ ym32) {
  __shared__ float smemf[16384];         // 64 KiB dbuf
  unsigned short* As = (unsigned short*)smemf;
  unsigned short* Bs = As + 16384;
  const int lin = blockIdx.x;
  const int bh = lin & 7, r0 = lin >> 3;            // r0 0..31
  const int ks = r0 >> 3, tile = r0 & 7;
  const int z = bh * 4 + ks, h = bh & 3;
  const int m0 = (tile & 3) * 128, n0 = (tile >> 2) * 128;
  f32x4 acc[4][4] = {};
  mfma_tile128_dbuf(xy + (size_t)bh * TT * NN + (size_t)m0 * NN + ks * 1024, NN,
                    decT + (size_t)h * DD * NN + (size_t)n0 * NN + ks * 1024, NN,
                    1024, acc, As, Bs);
  const int lane = threadIdx.x & 63, wave = threadIdx.x >> 6;
  const int fm = lane & 15, fq = lane >> 4;
  const int rw = (wave >> 1) << 6, cw = (wave & 1) << 6;
  float* C = ym32 + (size_t)z * TT * DD;
  #pragma unroll
  for (int ni = 0; ni < 4; ++ni) {
    int d = n0 + cw + ni * 16 + fm;
    #pragma unroll
    for (int mi = 0; mi < 4; ++mi) {
      int trow = m0 + rw + mi * 16 + (fq << 2);
      #pragma unroll
      for (int r = 0; r < 4; ++r)
        C[(size_t)(trow + r) * DD + d] = acc[mi][ni][r];
    }
  }
}

// x = LN(x + LN(sum of 16 partials)); emits f32 x, bf16 xbf, bf16 xT — one row/wave
__global__ __launch_bounds__(256) void k_ln2(float* __restrict__ x,
                                             const float* __restrict__ ym32,
                                             unsigned short* __restrict__ xbf,
                                             unsigned short* __restrict__ xTbf) {
  int row = blockIdx.x * 4 + (threadIdx.x >> 6);
  int lane = threadIdx.x & 63;
  int b = row >> 9, t = row & 511;
  int d0 = lane << 2;
  f32x4 y = {0.0f, 0.0f, 0.0f, 0.0f};
  size_t rbase = (size_t)t * DD + d0;
  #pragma unroll
  for (int p = 0; p < 16; ++p)
    y += *(const f32x4*)(ym32 + (size_t)(b * 16 + p) * TT * DD + rbase);
  float mu = wave_sum64(y.x + y.y + y.z + y.w) * (1.0f / DD);
  f32x4 d = y - mu;
  float var = wave_sum64(d.x * d.x + d.y * d.y + d.z * d.z + d.w * d.w) * (1.0f / DD);
  f32x4 ly = d * rsqrtf(var + 1e-5f);
  f32x4 xv = *(const f32x4*)(x + (size_t)row * DD + d0) + ly;
  float mu2 = wave_sum64(xv.x + xv.y + xv.z + xv.w) * (1.0f / DD);
  f32x4 d2 = xv - mu2;
  float var2 = wave_sum64(d2.x * d2.x + d2.y * d2.y + d2.z * d2.z + d2.w * d2.w) * (1.0f / DD);
  f32x4 r = d2 * rsqrtf(var2 + 1e-5f);
  *(f32x4*)(x + (size_t)row * DD + d0) = r;
  us4 rb;
  #pragma unroll
  for (int j = 0; j < 4; ++j) rb[j] = f2bf(r[j]);
  *(us4*)(xbf + (size_t)row * DD + d0) = rb;
  #pragma unroll
  for (int j = 0; j < 4; ++j)
    xTbf[((size_t)b * DD + d0 + j) * TT + t] = rb[j];
}

// ---------------- fused finals ----------------
// final1 = logits U trace_part U embed_part (independent, one dispatch)
__global__ __launch_bounds__(256) void k_final1(const float* __restrict__ x,
                                                const float* __restrict__ W,
                                                float* __restrict__ out_logits,
                                                const unsigned short* __restrict__ xy,
                                                float* __restrict__ tpart,
                                                float* __restrict__ epart) {
  __shared__ float xs[DD];
  const int blk = blockIdx.x;
  const int tid = threadIdx.x;
  if (blk < 1024) {
    // ---- logits (grid 1024)
    int row = blk;
    xs[tid] = x[(size_t)row * DD + tid];
    __syncthreads();
    float s = 0.0f;
    #pragma unroll 8
    for (int d = 0; d < DD; ++d) s = fmaf(xs[d], W[(size_t)d * VV + tid], s);
    out_logits[(size_t)row * VV + tid] = s;
  } else if (blk < 1280) {
    // ---- trace_part (grid 256)
    const int lin = blk - 1024;
    const int ts = lin & 15, nc = (lin >> 4) & 1, bh = lin >> 5;
    const int n0 = nc * 2048 + tid * 8;
    const size_t base = (size_t)bh * TT * NN + n0;
    float acc[8];
    #pragma unroll
    for (int j = 0; j < 8; ++j) acc[j] = 0.0f;
    for (int t = ts * 32; t < ts * 32 + 32; ++t) {
      us8 v = *(const us8*)(xy + base + (size_t)t * NN);
      #pragma unroll
      for (int j = 0; j < 8; ++j) acc[j] += bf2f(v[j]);
    }
    float* o = tpart + (size_t)(bh * 16 + ts) * NN + n0;
    #pragma unroll
    for (int j = 0; j < 8; ++j) o[j] = acc[j];
  } else {
    // ---- embed_part (grid 64)
    const int lin = blk - 1280;
    const int tc = lin & 31, b = lin >> 5;
    float s = 0.0f;
    #pragma unroll
    for (int i = 0; i < 16; ++i)
      s += x[(size_t)(b * TT + tc * 16 + i) * DD + tid];
    epart[(size_t)lin * DD + tid] = s;
  }
}

// final2 = trace_red U embed_red (grid 130)
__global__ __launch_bounds__(256) void k_final2(const float* __restrict__ tpart,
                                                float* __restrict__ out_trace,
                                                const float* __restrict__ epart,
                                                float* __restrict__ out_embed) {
  int idx = blockIdx.x * 256 + threadIdx.x;
  if (idx < 32768) {
    int bh = idx >> 12, n = idx & 4095;
    float s = 0.0f;
    #pragma unroll
    for (int ts = 0; ts < 16; ++ts)
      s += tpart[(size_t)(bh * 16 + ts) * NN + n];
    out_trace[idx] = s * (1.0f / TT);
  } else if (idx < 32768 + 512) {
    int i2 = idx - 32768;
    int b = i2 >> 8, d = i2 & 255;
    float s = 0.0f;
    #pragma unroll
    for (int tc = 0; tc < 32; ++tc)
      s += epart[(size_t)(b * 32 + tc) * DD + d];
    out_embed[i2] = s * (1.0f / TT);
  }
}

extern "C" void kernel_launch(void* const* d_in, const int* in_sizes, int n_in,
                              void* d_out, int out_size, void* d_ws, size_t ws_size,
                              hipStream_t stream) {
  const int*   ids  = (const int*)d_in[0];
  const float* tbl  = (const float*)d_in[1];
  const float* enc  = (const float*)d_in[2];
  const float* encv = (const float*)d_in[3];
  const float* dec  = (const float*)d_in[4];
  const float* lmh  = (const float*)d_in[5];

  // workspace layout (float units), ~180 MiB total
  float* ws   = (float*)d_ws;
  float* x    = ws;                                              //   262,144 f
  unsigned short* ykvbf = (unsigned short*)(x + 262144);         // 1,048,576 us
  float* ym32 = (float*)(ykvbf + 1048576);                       // 8,388,608 f (32 slabs used)
  unsigned short* xbf   = (unsigned short*)(ym32 + 8388608);     //   262,144 us
  unsigned short* xTbf  = xbf + 262144;                          //   262,144 us
  unsigned short* encT  = xTbf + 262144;                         // 4,194,304 us
  unsigned short* encvT = encT + 4194304;                        // 4,194,304 us
  unsigned short* decT  = encvT + 4194304;                       // 4,194,304 us
  unsigned short* xspbf = decT + 4194304;                        // 16,777,216 us
  unsigned short* qxybf = xspbf + 16777216;                      // 16,777,216 us
  unsigned int* cs = (unsigned int*)(qxybf + 16777216);          // 1,048,576 uint (4 MiB fp16 pairs)
  float* scp  = (float*)(cs + 2097152);                          // 8,388,608 f (32 MiB)
  float* ykvp = scp + 8388608;                                   // 4,194,304 f (16 MiB)
  // final-phase scratch (reuses scp region, free after last layer):
  float* tpart = scp;                                            // 524,288 f (trace partials)
  float* epart = scp + 524288;                                   // 16,384 f (embed partials)

  float* out_logits = (float*)d_out;
  float* out_embed  = out_logits + (size_t)BB * TT * VV;
  float* out_trace  = out_embed + (size_t)BB * DD;

  k_startup<<<8192, 256, 0, stream>>>(cs, enc, encv, dec, encT, encvT, decT,
                                      ids, tbl, x, xbf, xTbf);
  for (int l = 0; l < NLAYER; ++l) {
    k_enc        <<<1024, 256, 0, stream>>>(xbf, encT, cs, xspbf, qxybf);
    k_scores_part<<<320, 256, 0, stream>>>(qxybf, scp);
    k_ykv_part   <<<256, 256, 0, stream>>>(scp, xTbf, ykvp);
    k_ykv_red    <<<BH * TT / 4, 256, 0, stream>>>(ykvp, ykvbf);
    k_ysp_xy     <<<1024, 256, 0, stream>>>(ykvbf, encvT, xspbf, qxybf);
    k_ymlp       <<<256, 256, 0, stream>>>(qxybf, decT, ym32);
    k_ln2        <<<BB * TT / 4, 256, 0, stream>>>(x, ym32, xbf, xTbf);
  }
  k_final1<<<1344, 256, 0, stream>>>(x, lmh, out_logits, qxybf, tpart, epart);
  k_final2<<<130, 256, 0, stream>>>(tpart, out_trace, epart, out_embed);
}